// Round 1
// 1065.023 us; speedup vs baseline: 1.0590x; 1.0590x over previous
//
#include <hip/hip_runtime.h>
#include <stdint.h>

// Problem: lhs [1,16,4096,64] f32, rhs [1,16,64,4096] f32.
// rhs_t = swap(-1,-2) -> [1,16,4096,64]; BFP-quantize both along K=64
// (BLOCK=32, MBITS=8); C[h,m,n] = sum_k lhs_q[h,m,k]*rhs_q[h,n,k], fp32 out.
// BFP values q*2^(e-7), |q|<=128 are EXACT in bf16 -> bf16 MFMA is exact
// per-product; fp32 MFMA accumulate ~= reference fp32 accumulate.
//
// This rev: write-bound restructure of the GEMM.
//  - A/B tiles staged to LDS (reg-staged uint4, XOR-swizzled 16B granules)
//    -> global reads are contiguous 1KB/wave-instr instead of 32-line splinters.
//  - Epilogue transposes each wave's 32x128 acc tile through an 8KB LDS slice
//    (2 passes) -> global_store_dwordx4 in contiguous 512B row segments
//    (16 store instrs/wave vs 64 scalar dword stores).
//  - Bijective XCD swizzle: each XCD owns a contiguous 2048-block chunk
//    (2 heads); per-head A+B = 4MB = one XCD L2.
//  - LDS 32KB/block (C buffer overlays dead A/B staging) -> ~5 blocks/CU.

#define BH 16
#define MDIM 4096
#define NDIM 4096
#define KDIM 64

typedef __bf16 bf16x8 __attribute__((ext_vector_type(8)));
typedef float f32x16 __attribute__((ext_vector_type(16)));
typedef float f32x4 __attribute__((ext_vector_type(4)));

// exact floor(log2(maxabs)) via exponent field (exact for normals; the
// denormal-guard region only matters for all-zero blocks which are forced
// to 0 anyway by the maxabs>0 select).
__device__ __forceinline__ float bfp_quant_val(float x, float maxabs) {
  int e = (int)(__float_as_uint(fmaxf(maxabs, 1e-38f)) >> 23) - 127;
  e = e < -119 ? -119 : e;                         // keep step/rstep normal
  float rstep = __int_as_float((134 - e) << 23);   // 2^(7-e), exact
  float step  = __int_as_float((e + 120) << 23);   // 2^(e-7), exact
  float q = rintf(x * rstep);                      // round-half-even == np.round
  q = fminf(127.0f, fmaxf(-128.0f, q));
  return (maxabs > 0.0f) ? q * step : 0.0f;        // exactly bf16-representable
}

__device__ __forceinline__ unsigned short f32_to_bf16_exact(float r) {
  return (unsigned short)(__float_as_uint(r) >> 16);  // r is exact in bf16
}

// One wave per 64-element row; lanes 0-31 / 32-63 are the two BFP blocks.
__global__ __launch_bounds__(256) void quant_lhs_kernel(
    const float* __restrict__ in, unsigned short* __restrict__ out) {
  int tid = threadIdx.x;
  int lane = tid & 63;
  size_t row = (size_t)blockIdx.x * 4 + (tid >> 6);
  size_t idx = row * KDIM + lane;
  float x = in[idx];
  float v = fabsf(x);
#pragma unroll
  for (int off = 1; off < 32; off <<= 1)
    v = fmaxf(v, __shfl_xor(v, off));   // max within the 32-lane half
  out[idx] = f32_to_bf16_exact(bfp_quant_val(x, v));
}

// Fused transpose + quantize: thread owns column n of rhs[h,:,n] (the K axis
// of rhs_t), reads are coalesced across n, writes rhs_q[h][n][k] row-major.
__global__ __launch_bounds__(256) void quant_rhs_kernel(
    const float* __restrict__ in, unsigned short* __restrict__ out) {
  int h = blockIdx.y;
  int n = blockIdx.x * 256 + threadIdx.x;
  const float* src = in + (size_t)h * KDIM * NDIM + n;
  float x[KDIM];
#pragma unroll
  for (int k = 0; k < KDIM; ++k) x[k] = src[(size_t)k * NDIM];
  float ma0 = 0.0f, ma1 = 0.0f;
#pragma unroll
  for (int k = 0; k < 32; ++k) ma0 = fmaxf(ma0, fabsf(x[k]));
#pragma unroll
  for (int k = 32; k < 64; ++k) ma1 = fmaxf(ma1, fabsf(x[k]));
  unsigned short* dst = out + ((size_t)h * NDIM + n) * KDIM;
#pragma unroll
  for (int g = 0; g < 8; ++g) {
    union { unsigned short us[8]; uint4 v; } pk;
#pragma unroll
    for (int i = 0; i < 8; ++i) {
      int k = g * 8 + i;
      pk.us[i] = f32_to_bf16_exact(bfp_quant_val(x[k], (k < 32) ? ma0 : ma1));
    }
    ((uint4*)dst)[g] = pk.v;
  }
}

// 128x128 C tile per 256-thread block; wave w does rows [w*32, w*32+32) x 128
// cols. K=64 -> 4 MFMA k-steps of 16.
// Verified layouts (learn_hip m74/m101): A[m=lane&31][k=(lane>>5)*8+j],
// C/D: col=lane&31, row=(reg&3)+8*(reg>>2)+4*(lane>>5).
// LDS map: [0,16K) A tile 128rows x 128B, [16K,32K) B tile 128rows x 128B,
// 16B granules XOR-swizzled: phys_chunk = log_chunk ^ (row&7) (involution,
// applied at stage-write AND frag-read -> rule 21 both-sides).
// After MFMA+barrier, the same 32KB is reused as 4x 8KB per-wave C-transpose
// slices (16 rows x 128 f32 each), written twice (pass 0: rows 0-15, pass 1:
// rows 16-31 of the wave's 32-row band).
__global__ __launch_bounds__(256) void gemm_kernel(
    const unsigned short* __restrict__ aq, const unsigned short* __restrict__ bq,
    float* __restrict__ c) {
  __shared__ __align__(16) char smem[32768];

  // Bijective XCD swizzle: nwg = 16384 = 8 * 2048. Each XCD gets a contiguous
  // 2048-chunk => 2 heads per XCD, per-head A+B (4MB) fits one XCD L2.
  int wg = (int)blockIdx.x;
  wg = (wg & 7) * 2048 + (wg >> 3);
  const int h  = wg >> 10;          // 1024 blocks per head (32 x 32 tiles)
  const int bx = wg & 31;           // m-tile (fastest: consecutive blocks share B panel)
  const int by = (wg >> 5) & 31;    // n-tile
  const int m0 = bx * 128;
  const int n0 = by * 128;

  const int tid  = threadIdx.x;
  const int wave = tid >> 6;
  const int lane = tid & 63;
  const int l31  = lane & 31;
  const int hi   = lane >> 5;

  // ---- stage A,B tiles (16KB each) into LDS, swizzled ----
  // chunk index ci in [0,2048): ci<1024 -> A, else B. row = (ci&1023)>>3,
  // phys chunk p = ci&7 holds logical chunk p^(row&7).
  const unsigned short* abase = aq + (size_t)(h * MDIM + m0) * KDIM;
  const unsigned short* bbase = bq + (size_t)(h * NDIM + n0) * KDIM;
#pragma unroll
  for (int it = 0; it < 8; ++it) {
    int ci    = it * 256 + tid;          // 0..2047
    int local = ci & 1023;
    int row   = local >> 3;              // 0..127
    int p     = local & 7;
    int cl    = p ^ (row & 7);           // logical chunk living at phys p
    const unsigned short* src =
        ((ci < 1024) ? abase + (size_t)row * KDIM
                     : bbase + (size_t)row * KDIM) + cl * 8;
    uint4 v = *(const uint4*)src;        // contiguous 1KB per wave-instr
    *(uint4*)(smem + ci * 16) = v;       // linear dest, 2-way bank pairs (free)
  }
  __syncthreads();

  // ---- fragments from LDS + MFMA ----
  // logical A row = wave*32+l31, B row = j*32+l31; both ≡ l31 (mod 8), so the
  // XOR key is xo = l31&7. logical chunk for k-step s, half hi: hi + 2*s.
  const int xo = l31 & 7;
  const char* As = smem + (wave * 32 + l31) * 128;
  const char* Bs = smem + 16384 + l31 * 128;

  f32x16 acc[4] = {};
#pragma unroll
  for (int s = 0; s < 4; ++s) {
    const int co = ((hi + 2 * s) ^ xo) << 4;
    bf16x8 af = *(const bf16x8*)(As + co);
#pragma unroll
    for (int j = 0; j < 4; ++j) {
      bf16x8 bfr = *(const bf16x8*)(Bs + j * 4096 + co);
      acc[j] = __builtin_amdgcn_mfma_f32_32x32x16_bf16(af, bfr, acc[j], 0, 0, 0);
    }
  }
  __syncthreads();   // all frag ds_reads done; A/B LDS now dead -> C buffer

  // ---- epilogue: per-wave LDS transpose -> contiguous dwordx4 stores ----
  // Wave slice: 8KB = 16 rows x 128 f32 (row stride 512B). Two passes cover
  // the wave's 32 rows. Store instr = 2 contiguous 512B row segments.
  float* cslice = (float*)(smem + wave * 8192);
  float* cbase  = c + (size_t)h * MDIM * NDIM;
#pragma unroll
  for (int pass = 0; pass < 2; ++pass) {
#pragma unroll
    for (int j = 0; j < 4; ++j) {
#pragma unroll
      for (int rr = 0; rr < 8; ++rr) {
        int r = pass * 8 + rr;                             // acc reg index
        int lrow = (r & 3) + 8 * (r >> 2) + 4 * hi - pass * 16;  // 0..15
        cslice[lrow * 128 + j * 32 + l31] = acc[j][r];     // lanes->banks 1:1
      }
    }
    // RAW on cslice: compiler inserts lgkmcnt waits (same base object).
#pragma unroll
    for (int it = 0; it < 8; ++it) {
      int lrow = it * 2 + hi;                              // 0..15
      f32x4 v = *(const f32x4*)(cslice + lrow * 128 + l31 * 4);
      size_t grow = (size_t)(m0 + wave * 32 + pass * 16 + lrow);
      *(f32x4*)(cbase + grow * NDIM + n0 + l31 * 4) = v;
    }
    // WAR guard: pass-1 ds_writes must not overtake pass-0 ds_reads.
    asm volatile("s_waitcnt lgkmcnt(0)" ::: "memory");
  }
}

extern "C" void kernel_launch(void* const* d_in, const int* in_sizes, int n_in,
                              void* d_out, int out_size, void* d_ws, size_t ws_size,
                              hipStream_t stream) {
  const float* lhs = (const float*)d_in[0];
  const float* rhs = (const float*)d_in[1];
  float* out = (float*)d_out;

  unsigned short* aq = (unsigned short*)d_ws;                 // 8 MB
  unsigned short* bq = aq + (size_t)BH * MDIM * KDIM;         // +8 MB

  quant_lhs_kernel<<<dim3(BH * MDIM / 4), 256, 0, stream>>>(lhs, aq);
  quant_rhs_kernel<<<dim3(NDIM / 256, BH), 256, 0, stream>>>(rhs, bq);
  gemm_kernel<<<dim3(MDIM / 128 * NDIM / 128 * BH), 256, 0, stream>>>(aq, bq, out);
}